// Round 7
// baseline (65.717 us; speedup 1.0000x reference)
//
#include <hip/hip_runtime.h>
#include <hip/hip_cooperative_groups.h>

namespace cg = cooperative_groups;

// Problem constants (from reference): x[B,S,H], W*[H,H], b*[H], out[B,H]
#define BB 32
#define SS 1024
#define HH 256
#define SPLITS 16
#define ROWS (SS / SPLITS)  // 64 rows per A-phase block

// ---------------------------------------------------------------------------
// Math note: reference softmaxes over the QUERY axis (axis=1), so
// sum_q attn[b,q,k] == 1 for every (b,k). Then sum_q context = sum_k v.
// Hence out[b,h] = sum_h' Wv[h,h'] * (sum_s x[b,s,h']) + S * bv[h], exactly.
// Only x needs to be read (32 MB); Wq/bq/Wk/bk are provably unused.
//
// Structure lessons (R2-R6): per-CU streaming saturates at ~48 GB/s -> use
// all 256 CUs for phase A. Device fences serialize (R3: 57us). Atomics+
// memset lose (R4: 30us). Narrow kernels starve (R5/R1). Two wide nodes =
// 15.6us, of which ~7us is the node boundary (drain + gap + ramp). This
// round: ONE cooperative kernel, 512 blocks x 256 thr (2/CU, co-resident),
// grid.sync() between phases, blocks 0..255 do the wide B phase.
// ---------------------------------------------------------------------------

__global__ __launch_bounds__(256) void fused_coop_kernel(
    const float* __restrict__ x, const float* __restrict__ Wv,
    const float* __restrict__ bv, float* __restrict__ out,
    float* __restrict__ partials) {
    const int tid = threadIdx.x;
    __shared__ float4 lds[256];
    __shared__ float xsum[HH];

    // ---- Phase A: partial column sum of 64 rows of x ----
    {
        const int blk   = blockIdx.x;
        const int b     = blk >> 4;
        const int split = blk & 15;
        const int h4    = tid & 63;   // float4 column group
        const int ph    = tid >> 6;   // 0..3 row phase

        const float4* xb = reinterpret_cast<const float4*>(
            x + (size_t)b * SS * HH + (size_t)split * ROWS * HH);

        float4 acc = make_float4(0.f, 0.f, 0.f, 0.f);
        #pragma unroll
        for (int r = ph; r < ROWS; r += 4) {  // 16 independent loads in flight
            float4 v = xb[(size_t)r * (HH / 4) + h4];
            acc.x += v.x; acc.y += v.y; acc.z += v.z; acc.w += v.w;
        }

        lds[tid] = acc;
        __syncthreads();
        if (tid < 64) {
            float4 a0 = lds[tid];
            float4 a1 = lds[tid + 64];
            float4 a2 = lds[tid + 128];
            float4 a3 = lds[tid + 192];
            float4 r;
            r.x = (a0.x + a1.x) + (a2.x + a3.x);
            r.y = (a0.y + a1.y) + (a2.y + a3.y);
            r.z = (a0.z + a1.z) + (a2.z + a3.z);
            r.w = (a0.w + a1.w) + (a2.w + a3.w);
            reinterpret_cast<float4*>(
                partials + ((size_t)b * SPLITS + split) * HH)[h4] = r;
        }
    }

    // ---- Grid-wide barrier (cooperative launch) ----
    cg::this_grid().sync();

    // ---- Phase B: blocks 0..255, one per (batch, 32-h chunk) ----
    if (blockIdx.x < BB * 8) {
        const int blk = blockIdx.x;
        const int b   = blk >> 3;          // batch
        const int hc  = (blk & 7) * 32;    // h-chunk base
        const int g   = tid & 63;          // float4 group
        const int sp  = tid >> 6;          // 0..3 split phase

        const float4* pb = reinterpret_cast<const float4*>(
            partials + (size_t)b * SPLITS * HH);

        float4 a4 = make_float4(0.f, 0.f, 0.f, 0.f);
        #pragma unroll
        for (int c = sp; c < SPLITS; c += 4) {
            float4 v = pb[(size_t)c * (HH / 4) + g];
            a4.x += v.x; a4.y += v.y; a4.z += v.z; a4.w += v.w;
        }

        lds[tid] = a4;
        __syncthreads();
        if (tid < 64) {
            float4 a0 = lds[tid];
            float4 a1 = lds[tid + 64];
            float4 a2 = lds[tid + 128];
            float4 a3 = lds[tid + 192];
            float4 r;
            r.x = (a0.x + a1.x) + (a2.x + a3.x);
            r.y = (a0.y + a1.y) + (a2.y + a3.y);
            r.z = (a0.z + a1.z) + (a2.z + a3.z);
            r.w = (a0.w + a1.w) + (a2.w + a3.w);
            reinterpret_cast<float4*>(xsum)[tid] = r;
        }
        __syncthreads();

        // 32 outputs: h = hc + (tid>>3); 8 lanes (seg) split the 256-dot
        const int h   = hc + (tid >> 3);
        const int seg = tid & 7;
        const float4* wrow = reinterpret_cast<const float4*>(
            Wv + (size_t)h * HH + (size_t)seg * 32);
        const float4* xs = reinterpret_cast<const float4*>(
            xsum + (size_t)seg * 32);

        float o = 0.f;
        #pragma unroll
        for (int i = 0; i < 8; ++i) {
            float4 w  = wrow[i];
            float4 xv = xs[i];
            o += w.x * xv.x + w.y * xv.y + w.z * xv.z + w.w * xv.w;
        }
        o += __shfl_xor(o, 1);
        o += __shfl_xor(o, 2);
        o += __shfl_xor(o, 4);
        if (seg == 0)
            out[(size_t)b * HH + h] = o + (float)SS * bv[h];
    }
}

extern "C" void kernel_launch(void* const* d_in, const int* in_sizes, int n_in,
                              void* d_out, int out_size, void* d_ws, size_t ws_size,
                              hipStream_t stream) {
    // setup_inputs order: x, Wq, bq, Wk, bk, Wv, bv
    const float* x  = (const float*)d_in[0];
    const float* Wv = (const float*)d_in[5];
    const float* bv = (const float*)d_in[6];
    float* out = (float*)d_out;
    float* partials = (float*)d_ws;  // BB*SPLITS*HH f32 = 512 KB

    void* args[] = {(void*)&x, (void*)&Wv, (void*)&bv, (void*)&out,
                    (void*)&partials};
    hipLaunchCooperativeKernel((const void*)fused_coop_kernel,
                               dim3(BB * SPLITS), dim3(256), args, 0, stream);
}

// Round 8
// 36.512 us; speedup vs baseline: 1.7999x; 1.7999x over previous
//
#include <hip/hip_runtime.h>

// Problem constants (from reference): x[B,S,H], W*[H,H], b*[H], out[B,H]
#define BB 32
#define SS 1024
#define HH 256
#define SPLITS 16
#define ROWS (SS / SPLITS)  // 64 rows per A-phase block

// ---------------------------------------------------------------------------
// Math: softmax is over the QUERY axis -> out[b,h] = Wv . (sum_s x[b,s,:]) +
// S*bv[h], exactly. Only x (32 MB) must be read.
//
// Sync-mechanism ledger on this 8-XCD chip:
//   R3 __threadfence per storer: 57us   (bulk L2 writeback per fence)
//   R4 memset + 131K contended atomicAdd + 131MB Wv: 30us
//   R7 cooperative grid.sync(): 66us    (same bulk maintenance internally)
// This round: NO cache-maintenance instructions. Agent-scope RELAXED
// stores/loads are per-access coherent (write-through / read-through the
// coherence point); ordering store->flag via __syncthreads' vmcnt(0) drain;
// ONE relaxed agent fetch_add per block (512 total). B-phase blocks poll
// with relaxed agent loads + s_sleep. __launch_bounds__(256,2) => 2 blocks/
// CU co-resident for all 512 blocks => no spin deadlock (G16-safe).
// ---------------------------------------------------------------------------

__global__ __launch_bounds__(256, 2) void fused_agent_kernel(
    const float* __restrict__ x, const float* __restrict__ Wv,
    const float* __restrict__ bv, float* __restrict__ out,
    float* __restrict__ partials, unsigned int* __restrict__ counters) {
    const int tid = threadIdx.x;
    __shared__ float4 lds[256];
    __shared__ float xsum[HH];

    // ---- Phase A: partial column sum of 64 rows of x ----
    {
        const int blk   = blockIdx.x;
        const int b     = blk >> 4;
        const int split = blk & 15;
        const int h4    = tid & 63;
        const int ph    = tid >> 6;

        const float4* xb = reinterpret_cast<const float4*>(
            x + (size_t)b * SS * HH + (size_t)split * ROWS * HH);

        float4 acc = make_float4(0.f, 0.f, 0.f, 0.f);
        #pragma unroll
        for (int r = ph; r < ROWS; r += 4) {
            float4 v = xb[(size_t)r * (HH / 4) + h4];
            acc.x += v.x; acc.y += v.y; acc.z += v.z; acc.w += v.w;
        }

        lds[tid] = acc;
        __syncthreads();
        if (tid < 64) {
            float4 a0 = lds[tid];
            float4 a1 = lds[tid + 64];
            float4 a2 = lds[tid + 128];
            float4 a3 = lds[tid + 192];
            float4 r;
            r.x = (a0.x + a1.x) + (a2.x + a3.x);
            r.y = (a0.y + a1.y) + (a2.y + a3.y);
            r.z = (a0.z + a1.z) + (a2.z + a3.z);
            r.w = (a0.w + a1.w) + (a2.w + a3.w);
            float* dst = partials + ((size_t)b * SPLITS + split) * HH + h4 * 4;
            // Per-access coherent stores (no cache maintenance).
            __hip_atomic_store(dst + 0, r.x, __ATOMIC_RELAXED, __HIP_MEMORY_SCOPE_AGENT);
            __hip_atomic_store(dst + 1, r.y, __ATOMIC_RELAXED, __HIP_MEMORY_SCOPE_AGENT);
            __hip_atomic_store(dst + 2, r.z, __ATOMIC_RELAXED, __HIP_MEMORY_SCOPE_AGENT);
            __hip_atomic_store(dst + 3, r.w, __ATOMIC_RELAXED, __HIP_MEMORY_SCOPE_AGENT);
        }
        // __syncthreads drains vmcnt(0): the agent stores above have reached
        // the coherence point before any thread proceeds.
        __syncthreads();
        if (tid == 0)
            __hip_atomic_fetch_add(&counters[b], 1u, __ATOMIC_RELAXED,
                                   __HIP_MEMORY_SCOPE_AGENT);
    }

    // ---- Phase B: blocks 0..255, one per (batch, 32-h chunk) ----
    if (blockIdx.x < BB * 8) {
        const int blk = blockIdx.x;
        const int b2  = blk >> 3;
        const int hc  = (blk & 7) * 32;

        if (tid == 0) {
            while (__hip_atomic_load(&counters[b2], __ATOMIC_RELAXED,
                                     __HIP_MEMORY_SCOPE_AGENT) < SPLITS)
                __builtin_amdgcn_s_sleep(2);
        }
        __syncthreads();  // all threads held until arrival complete

        const int g  = tid & 63;
        const int sp = tid >> 6;
        const float* pb = partials + (size_t)b2 * SPLITS * HH;

        float4 a4 = make_float4(0.f, 0.f, 0.f, 0.f);
        #pragma unroll
        for (int c = sp; c < SPLITS; c += 4) {
            const float* p = pb + (size_t)c * HH + g * 4;
            a4.x += __hip_atomic_load(p + 0, __ATOMIC_RELAXED, __HIP_MEMORY_SCOPE_AGENT);
            a4.y += __hip_atomic_load(p + 1, __ATOMIC_RELAXED, __HIP_MEMORY_SCOPE_AGENT);
            a4.z += __hip_atomic_load(p + 2, __ATOMIC_RELAXED, __HIP_MEMORY_SCOPE_AGENT);
            a4.w += __hip_atomic_load(p + 3, __ATOMIC_RELAXED, __HIP_MEMORY_SCOPE_AGENT);
        }

        lds[tid] = a4;
        __syncthreads();
        if (tid < 64) {
            float4 a0 = lds[tid];
            float4 a1 = lds[tid + 64];
            float4 a2 = lds[tid + 128];
            float4 a3 = lds[tid + 192];
            float4 r;
            r.x = (a0.x + a1.x) + (a2.x + a3.x);
            r.y = (a0.y + a1.y) + (a2.y + a3.y);
            r.z = (a0.z + a1.z) + (a2.z + a3.z);
            r.w = (a0.w + a1.w) + (a2.w + a3.w);
            reinterpret_cast<float4*>(xsum)[tid] = r;
        }
        __syncthreads();

        const int h   = hc + (tid >> 3);
        const int seg = tid & 7;
        const float4* wrow = reinterpret_cast<const float4*>(
            Wv + (size_t)h * HH + (size_t)seg * 32);
        const float4* xs = reinterpret_cast<const float4*>(
            xsum + (size_t)seg * 32);

        float o = 0.f;
        #pragma unroll
        for (int i = 0; i < 8; ++i) {
            float4 w  = wrow[i];
            float4 xv = xs[i];
            o += w.x * xv.x + w.y * xv.y + w.z * xv.z + w.w * xv.w;
        }
        o += __shfl_xor(o, 1);
        o += __shfl_xor(o, 2);
        o += __shfl_xor(o, 4);
        if (seg == 0)
            out[(size_t)b2 * HH + h] = o + (float)SS * bv[h];
    }
}

extern "C" void kernel_launch(void* const* d_in, const int* in_sizes, int n_in,
                              void* d_out, int out_size, void* d_ws, size_t ws_size,
                              hipStream_t stream) {
    // setup_inputs order: x, Wq, bq, Wk, bk, Wv, bv
    const float* x  = (const float*)d_in[0];
    const float* Wv = (const float*)d_in[5];
    const float* bv = (const float*)d_in[6];
    float* out = (float*)d_out;

    // ws layout: partials [BB][SPLITS][HH] f32 (512 KB), then counters [BB].
    float* partials = (float*)d_ws;
    unsigned int* counters =
        (unsigned int*)((char*)d_ws + (size_t)BB * SPLITS * HH * sizeof(float));

    // Counters must start at 0 every call (ws poisoned to 0xAA once).
    hipMemsetAsync(counters, 0, BB * sizeof(unsigned int), stream);

    fused_agent_kernel<<<BB * SPLITS, 256, 0, stream>>>(
        x, Wv, bv, out, partials, counters);
}

// Round 9
// 16.098 us; speedup vs baseline: 4.0824x; 2.2682x over previous
//
#include <hip/hip_runtime.h>

// Problem constants (from reference): x[B,S,H], W*[H,H], b*[H], out[B,H]
#define BB 32
#define SS 1024
#define HH 256
#define SPLITS 32
#define ROWS (SS / SPLITS)  // 32 rows per A-block

// ---------------------------------------------------------------------------
// Math note: reference softmaxes over the QUERY axis (axis=1), so
// sum_q attn[b,q,k] == 1 for every (b,k). Then sum_q context = sum_k v.
// Hence out[b,h] = sum_h' Wv[h,h'] * (sum_s x[b,s,h']) + S * bv[h], exactly.
// Only x needs to be read (32 MB); Wq/bq/Wk/bk are provably unused.
//
// Structure: two wide graph nodes. Phase-handoff ledger on this 8-XCD chip:
// graph edge ~4-7us << atomic fan-in (R4: 30us) << agent-scope spin (R8:
// 36.5us) << device fence (R3: 57us) << cooperative grid.sync (R7: 66us).
// Per-CU streaming saturates ~48 GB/s (R5) -> both phases must span all
// 256 CUs. This round: A at 1024 blocks (4/CU, 16 waves/CU) instead of 512
// (R2's SPLITS=64 regression was the NARROW B reading 4x partials, not A).
// ---------------------------------------------------------------------------

// Kernel A: partial column sums of x over S. 1024 blocks x 256 thr.
// partials layout: [BB][SPLITS][HH] f32 (1 MB in d_ws).
__global__ __launch_bounds__(256) void xsum_partial_kernel(
    const float* __restrict__ x, float* __restrict__ partials) {
    const int blk   = blockIdx.x;
    const int b     = blk >> 5;          // batch
    const int split = blk & (SPLITS - 1);
    const int tid   = threadIdx.x;
    const int h4    = tid & 63;   // float4 column group (64 cover 256 floats)
    const int ph    = tid >> 6;   // 0..3 row phase

    const float4* xb = reinterpret_cast<const float4*>(
        x + (size_t)b * SS * HH + (size_t)split * ROWS * HH);

    float4 acc = make_float4(0.f, 0.f, 0.f, 0.f);
    #pragma unroll
    for (int r = ph; r < ROWS; r += 4) {  // 8 independent loads in flight
        float4 v = xb[(size_t)r * (HH / 4) + h4];
        acc.x += v.x; acc.y += v.y; acc.z += v.z; acc.w += v.w;
    }

    __shared__ float4 lds[256];
    lds[tid] = acc;
    __syncthreads();
    if (tid < 64) {
        float4 a0 = lds[tid];
        float4 a1 = lds[tid + 64];
        float4 a2 = lds[tid + 128];
        float4 a3 = lds[tid + 192];
        float4 r;
        r.x = (a0.x + a1.x) + (a2.x + a3.x);
        r.y = (a0.y + a1.y) + (a2.y + a3.y);
        r.z = (a0.z + a1.z) + (a2.z + a3.z);
        r.w = (a0.w + a1.w) + (a2.w + a3.w);
        reinterpret_cast<float4*>(
            partials + ((size_t)b * SPLITS + split) * HH)[h4] = r;
    }
}

// Kernel B: 256 blocks x 256 thr (one per (batch, 32-h chunk), all CUs).
// Reduce this batch's 32 partials -> xsum[256] in LDS (8 loads/thread),
// then 32 outputs via 8-lane-split dot + __shfl_xor reduce.
__global__ __launch_bounds__(256) void out_kernel(
    const float* __restrict__ partials, const float* __restrict__ Wv,
    const float* __restrict__ bv, float* __restrict__ out) {
    const int blk = blockIdx.x;
    const int b   = blk >> 3;          // batch
    const int hc  = (blk & 7) * 32;    // h-chunk base
    const int tid = threadIdx.x;

    // ---- reduce partials[b][32][256] -> xsum ----
    const int g  = tid & 63;   // float4 group
    const int sp = tid >> 6;   // 0..3 split phase
    const float4* pb = reinterpret_cast<const float4*>(
        partials + (size_t)b * SPLITS * HH);

    float4 a4 = make_float4(0.f, 0.f, 0.f, 0.f);
    #pragma unroll
    for (int c = sp; c < SPLITS; c += 4) {
        float4 v = pb[(size_t)c * (HH / 4) + g];
        a4.x += v.x; a4.y += v.y; a4.z += v.z; a4.w += v.w;
    }

    __shared__ float4 lds[256];
    __shared__ float xsum[HH];
    lds[tid] = a4;
    __syncthreads();
    if (tid < 64) {
        float4 a0 = lds[tid];
        float4 a1 = lds[tid + 64];
        float4 a2 = lds[tid + 128];
        float4 a3 = lds[tid + 192];
        float4 r;
        r.x = (a0.x + a1.x) + (a2.x + a3.x);
        r.y = (a0.y + a1.y) + (a2.y + a3.y);
        r.z = (a0.z + a1.z) + (a2.z + a3.z);
        r.w = (a0.w + a1.w) + (a2.w + a3.w);
        reinterpret_cast<float4*>(xsum)[tid] = r;
    }
    __syncthreads();

    // ---- dot: h = hc + (tid>>3), 8 lanes (seg=tid&7) split the 256-dot ----
    const int h   = hc + (tid >> 3);
    const int seg = tid & 7;           // 32-element segment
    const float4* wrow = reinterpret_cast<const float4*>(
        Wv + (size_t)h * HH + (size_t)seg * 32);
    const float4* xs = reinterpret_cast<const float4*>(xsum + (size_t)seg * 32);

    float o = 0.f;
    #pragma unroll
    for (int i = 0; i < 8; ++i) {      // 8 float4 = 32 MACs
        float4 w  = wrow[i];
        float4 xv = xs[i];
        o += w.x * xv.x + w.y * xv.y + w.z * xv.z + w.w * xv.w;
    }
    o += __shfl_xor(o, 1);
    o += __shfl_xor(o, 2);
    o += __shfl_xor(o, 4);
    if (seg == 0)
        out[(size_t)b * HH + h] = o + (float)SS * bv[h];
}

extern "C" void kernel_launch(void* const* d_in, const int* in_sizes, int n_in,
                              void* d_out, int out_size, void* d_ws, size_t ws_size,
                              hipStream_t stream) {
    // setup_inputs order: x, Wq, bq, Wk, bk, Wv, bv
    const float* x  = (const float*)d_in[0];
    const float* Wv = (const float*)d_in[5];
    const float* bv = (const float*)d_in[6];
    float* out = (float*)d_out;
    float* partials = (float*)d_ws;  // BB*SPLITS*HH f32 = 1 MB

    xsum_partial_kernel<<<BB * SPLITS, 256, 0, stream>>>(x, partials);
    out_kernel<<<BB * 8, 256, 0, stream>>>(partials, Wv, bv, out);
}

// Round 10
// 15.713 us; speedup vs baseline: 4.1822x; 1.0245x over previous
//
#include <hip/hip_runtime.h>

// Problem constants (from reference): x[B,S,H], W*[H,H], b*[H], out[B,H]
#define BB 32
#define SS 1024
#define HH 256
#define SPLITS 16
#define ROWS (SS / SPLITS)  // 64 rows per A-block

// ---------------------------------------------------------------------------
// Math note: reference softmaxes over the QUERY axis (axis=1), so
// sum_q attn[b,q,k] == 1 for every (b,k). Then sum_q context = sum_k v.
// Hence out[b,h] = sum_h' Wv[h,h'] * (sum_s x[b,s,h']) + S * bv[h], exactly.
// Only x needs to be read (32 MB); Wq/bq/Wk/bk are provably unused.
//
// Final structure (best of R1-R9 ledger): two wide graph nodes.
//   - Per-CU streaming saturates ~48 GB/s (R5) -> both phases span all CUs.
//   - Graph edge ~4-7us is the CHEAPEST phase handoff on this 8-XCD chip:
//     atomic fan-in 30us (R4) < agent spin 36.5us (R8) < fence 57us (R3)
//     < cooperative grid.sync 66us (R7).
//   - A-occupancy beyond 2 blocks/CU is not a lever (R9: SPLITS=32 +0.5us).
// ---------------------------------------------------------------------------

// Kernel A: partial column sums of x over S. 512 blocks x 256 thr, all CUs.
// partials layout: [BB][SPLITS][HH] f32 (512 KB in d_ws).
__global__ __launch_bounds__(256) void xsum_partial_kernel(
    const float* __restrict__ x, float* __restrict__ partials) {
    const int blk   = blockIdx.x;
    const int b     = blk >> 4;
    const int split = blk & 15;
    const int tid   = threadIdx.x;
    const int h4    = tid & 63;   // float4 column group (64 cover 256 floats)
    const int ph    = tid >> 6;   // 0..3 row phase

    const float4* xb = reinterpret_cast<const float4*>(
        x + (size_t)b * SS * HH + (size_t)split * ROWS * HH);

    float4 acc = make_float4(0.f, 0.f, 0.f, 0.f);
    #pragma unroll
    for (int r = ph; r < ROWS; r += 4) {  // 16 independent loads in flight
        float4 v = xb[(size_t)r * (HH / 4) + h4];
        acc.x += v.x; acc.y += v.y; acc.z += v.z; acc.w += v.w;
    }

    __shared__ float4 lds[256];
    lds[tid] = acc;
    __syncthreads();
    if (tid < 64) {
        float4 a0 = lds[tid];
        float4 a1 = lds[tid + 64];
        float4 a2 = lds[tid + 128];
        float4 a3 = lds[tid + 192];
        float4 r;
        r.x = (a0.x + a1.x) + (a2.x + a3.x);
        r.y = (a0.y + a1.y) + (a2.y + a3.y);
        r.z = (a0.z + a1.z) + (a2.z + a3.z);
        r.w = (a0.w + a1.w) + (a2.w + a3.w);
        reinterpret_cast<float4*>(
            partials + ((size_t)b * SPLITS + split) * HH)[h4] = r;
    }
}

// Kernel B: 256 blocks x 256 thr (one per (batch, 32-h chunk), all CUs).
// Each block: reduce this batch's 16 partials -> xsum[256] in LDS (4 loads/
// thread), then 32 outputs via 8-lane-split dot + __shfl_xor reduce.
__global__ __launch_bounds__(256) void out_kernel(
    const float* __restrict__ partials, const float* __restrict__ Wv,
    const float* __restrict__ bv, float* __restrict__ out) {
    const int blk = blockIdx.x;
    const int b   = blk >> 3;          // batch
    const int hc  = (blk & 7) * 32;    // h-chunk base
    const int tid = threadIdx.x;

    // ---- reduce partials[b][16][256] -> xsum ----
    const int g  = tid & 63;   // float4 group
    const int sp = tid >> 6;   // 0..3 split phase
    const float4* pb = reinterpret_cast<const float4*>(
        partials + (size_t)b * SPLITS * HH);

    float4 a4 = make_float4(0.f, 0.f, 0.f, 0.f);
    #pragma unroll
    for (int c = sp; c < SPLITS; c += 4) {
        float4 v = pb[(size_t)c * (HH / 4) + g];
        a4.x += v.x; a4.y += v.y; a4.z += v.z; a4.w += v.w;
    }

    __shared__ float4 lds[256];
    __shared__ float xsum[HH];
    lds[tid] = a4;
    __syncthreads();
    if (tid < 64) {
        float4 a0 = lds[tid];
        float4 a1 = lds[tid + 64];
        float4 a2 = lds[tid + 128];
        float4 a3 = lds[tid + 192];
        float4 r;
        r.x = (a0.x + a1.x) + (a2.x + a3.x);
        r.y = (a0.y + a1.y) + (a2.y + a3.y);
        r.z = (a0.z + a1.z) + (a2.z + a3.z);
        r.w = (a0.w + a1.w) + (a2.w + a3.w);
        reinterpret_cast<float4*>(xsum)[tid] = r;
    }
    __syncthreads();

    // ---- dot: h = hc + (tid>>3), 8 lanes (seg=tid&7) split the 256-dot ----
    const int h   = hc + (tid >> 3);
    const int seg = tid & 7;           // 32-element segment
    const float4* wrow = reinterpret_cast<const float4*>(
        Wv + (size_t)h * HH + (size_t)seg * 32);
    const float4* xs = reinterpret_cast<const float4*>(xsum + (size_t)seg * 32);

    float o = 0.f;
    #pragma unroll
    for (int i = 0; i < 8; ++i) {      // 8 float4 = 32 MACs
        float4 w  = wrow[i];
        float4 xv = xs[i];
        o += w.x * xv.x + w.y * xv.y + w.z * xv.z + w.w * xv.w;
    }
    // reduce across the 8 segment lanes (consecutive lanes, same wave)
    o += __shfl_xor(o, 1);
    o += __shfl_xor(o, 2);
    o += __shfl_xor(o, 4);
    if (seg == 0)
        out[(size_t)b * HH + h] = o + (float)SS * bv[h];
}

extern "C" void kernel_launch(void* const* d_in, const int* in_sizes, int n_in,
                              void* d_out, int out_size, void* d_ws, size_t ws_size,
                              hipStream_t stream) {
    // setup_inputs order: x, Wq, bq, Wk, bk, Wv, bv
    const float* x  = (const float*)d_in[0];
    const float* Wv = (const float*)d_in[5];
    const float* bv = (const float*)d_in[6];
    float* out = (float*)d_out;
    float* partials = (float*)d_ws;  // BB*SPLITS*HH f32 = 512 KB

    xsum_partial_kernel<<<BB * SPLITS, 256, 0, stream>>>(x, partials);
    out_kernel<<<BB * 8, 256, 0, stream>>>(partials, Wv, bv, out);
}